// Round 1
// baseline (101.623 us; speedup 1.0000x reference)
//
#include <hip/hip_runtime.h>

#define FSRS_S_MIN 0.01f
#define FSRS_S_MAX 36500.0f
#define T_LEN 64
#define CHUNK 8

__global__ __launch_bounds__(256) void fsrs2_kernel(
    const float* __restrict__ inputs,    // [64, B, 2] (elapsed, rating)
    const float* __restrict__ delta_ts,  // [B]
    const float* __restrict__ w,         // [14]
    const int*   __restrict__ seq_lens,  // [B]
    float* __restrict__ out,             // [3, B]
    int B)
{
    const int b = blockIdx.x * blockDim.x + threadIdx.x;
    if (b >= B) return;

    // ---- uniform scalar constants (compiler: s_load, folded) ----
    const float w0 = w[0],  w1 = w[1],  w2 = w[2],  w3 = w[3];
    const float w4 = w[4],  w5 = w[5],  w6 = w[6],  w7 = w[7];
    const float w8 = w[8],  w9 = w[9],  w10 = w[10], w11 = w[11];
    const float w12 = w[12], w13 = w[13];

    const float LOG2E = 1.4426950408889634f;
    const float L09   = -0.15200309344504997f;   // log2(0.9)

    // s0 = w0*(w1*(rating-1)+1) = a0*rating + b0
    const float a0 = w0 * w1;
    const float b0 = w0 * (1.0f - w1);
    // d0(pre-clip) = w2*(w3*(rating-4)+1) = a1*rating + b1
    const float a1 = w2 * w3;
    const float b1 = w2 * (1.0f - 4.0f * w3);
    // nd mix: nd = w5*(w2*(1-w3)) + (1-w5)*nd
    const float c_nd = 1.0f - w5;
    const float b_nd = w5 * (w2 * (1.0f - w3));
    // exponent-domain constants
    const float lw6 = w6  * LOG2E;   // exp(w6)        = exp2(lw6)
    const float g9  = w9  * LOG2E;   // exp((1-r)*w9)  = exp2((1-r)*g9)
    const float g13 = w13 * LOG2E;   // exp((1-r)*w13) = exp2((1-r)*g13)

    const int Lm1 = seq_lens[b] - 1;             // in [0, 63]

    const float2* __restrict__ inp = (const float2*)inputs;  // [64, B]

    // ---- register double-buffer of CHUNK timesteps ----
    float2 cur[CHUNK], nxt[CHUNK];
    #pragma unroll
    for (int i = 0; i < CHUNK; ++i) cur[i] = inp[(size_t)i * B + b];

    float s = 0.0f, d = 0.0f;
    float res_s = 0.0f, res_d = 0.0f;

    #pragma unroll
    for (int c = 0; c < T_LEN / CHUNK; ++c) {
        if (c + 1 < T_LEN / CHUNK) {
            #pragma unroll
            for (int i = 0; i < CHUNK; ++i)
                nxt[i] = inp[(size_t)((c + 1) * CHUNK + i) * B + b];
        }
        #pragma unroll
        for (int i = 0; i < CHUNK; ++i) {
            const int t = c * CHUNK + i;          // compile-time constant
            const float elapsed = cur[i].x;
            const float rating  = cur[i].y;

            const float ss     = fmaxf(s, FSRS_S_MIN);
            const float inv_ss = __builtin_amdgcn_rcpf(ss);
            const float r      = exp2f(elapsed * inv_ss * L09);   // 0.9^(elapsed/ss)

            float nd = fmaf(w4, rating - 3.0f, d);
            nd = fmaf(c_nd, nd, b_nd);
            nd = fminf(fmaxf(nd, 1.0f), 10.0f);

            const float lss = log2f(ss);
            const float lnd = log2f(nd);
            const float omr = 1.0f - r;

            // succ = ss * (1 + exp(w6)*nd^w7*ss^w8 * (exp(omr*w9)-1))
            const float powS = exp2f(fmaf(w7, lnd, fmaf(w8, lss, lw6)));
            const float gain = exp2f(omr * g9) - 1.0f;
            const float succ = ss * fmaf(powS, gain, 1.0f);

            // fail = w10 * nd^w11 * ss^w12 * (exp(omr*w13)-1)
            const float powF = exp2f(fmaf(w11, lnd, w12 * lss));
            const float gF   = exp2f(omr * g13) - 1.0f;
            const float fail = (w10 * powF) * gF;

            float ns = (rating > 1.0f) ? succ : fail;

            if (t == 0) {   // folds at compile time: first-step override
                ns = fmaf(a0, rating, b0);
                nd = fminf(fmaxf(fmaf(a1, rating, b1), 1.0f), 10.0f);
            }

            s = fminf(fmaxf(ns, FSRS_S_MIN), FSRS_S_MAX);
            d = nd;

            if (t == Lm1) { res_s = s; res_d = d; }   // 2 cndmask
        }
        if (c + 1 < T_LEN / CHUNK) {
            #pragma unroll
            for (int i = 0; i < CHUNK; ++i) cur[i] = nxt[i];
        }
    }

    const float dt  = delta_ts[b];
    const float ret = exp2f(dt * __builtin_amdgcn_rcpf(res_s) * L09);

    out[b]         = ret;
    out[B + b]     = res_s;
    out[2 * B + b] = res_d;
}

extern "C" void kernel_launch(void* const* d_in, const int* in_sizes, int n_in,
                              void* d_out, int out_size, void* d_ws, size_t ws_size,
                              hipStream_t stream) {
    const float* inputs   = (const float*)d_in[0];   // [64, B, 2] f32
    const float* delta_ts = (const float*)d_in[1];   // [B] f32
    const float* w        = (const float*)d_in[2];   // [14] f32
    const int*   seq_lens = (const int*)d_in[3];     // [B] i32
    float* out = (float*)d_out;                      // [3, B] f32

    const int B = in_sizes[1];
    const int block = 256;
    const int grid  = (B + block - 1) / block;
    fsrs2_kernel<<<grid, block, 0, stream>>>(inputs, delta_ts, w, seq_lens, out, B);
}

// Round 4
// 98.990 us; speedup vs baseline: 1.0266x; 1.0266x over previous
//
#include <hip/hip_runtime.h>

#define FSRS_S_MIN 0.01f
#define FSRS_S_MAX 36500.0f
#define T_LEN 64
#define CHUNK 8
#define NCHUNK (T_LEN / CHUNK)

__global__ __launch_bounds__(256, 2) void fsrs2_kernel(
    const float* __restrict__ inputs,    // [64, B, 2] (elapsed, rating)
    const float* __restrict__ delta_ts,  // [B]
    const float* __restrict__ w,         // [14]
    const int*   __restrict__ seq_lens,  // [B]
    float* __restrict__ out,             // [3, B]
    int B)
{
    const int b = blockIdx.x * blockDim.x + threadIdx.x;
    if (b >= B) return;

    // Issue the small per-thread loads first so they are long done by epilogue.
    const int   Lm1 = seq_lens[b] - 1;           // in [0, 63]
    const float dt  = delta_ts[b];

    // ---- uniform scalar constants ----
    const float w0 = w[0],  w1 = w[1],  w2 = w[2],  w3 = w[3];
    const float w4 = w[4],  w5 = w[5],  w6 = w[6],  w7 = w[7];
    const float w8 = w[8],  w9 = w[9],  w10 = w[10], w11 = w[11];
    const float w12 = w[12], w13 = w[13];

    const float LOG2E = 1.4426950408889634f;
    const float L09   = -0.15200309344504997f;   // log2(0.9)

    // s0 = w0*(w1*(rating-1)+1) = a0*rating + b0
    const float a0 = w0 * w1;
    const float b0 = w0 * (1.0f - w1);
    // d0(pre-clip) = w2*(w3*(rating-4)+1) = a1*rating + b1
    const float a1 = w2 * w3;
    const float b1 = w2 * (1.0f - 4.0f * w3);
    // nd mix: nd = w5*(w2*(1-w3)) + (1-w5)*nd
    const float c_nd = 1.0f - w5;
    const float b_nd = w5 * (w2 * (1.0f - w3));
    // exponent-domain constants
    const float lw6 = w6  * LOG2E;   // exp(w6)        = exp2(lw6)
    const float g9  = w9  * LOG2E;   // exp((1-r)*w9)  = exp2((1-r)*g9)
    const float g13 = w13 * LOG2E;   // exp((1-r)*w13) = exp2((1-r)*g13)

    const float2* __restrict__ inp = (const float2*)inputs;  // [64, B]

    // ---- 3-buffer register rotation, prefetch depth 2 (all static indices) ----
    float2 buf[3][CHUNK];
    #pragma unroll
    for (int i = 0; i < CHUNK; ++i) buf[0][i] = inp[(size_t)(0 * CHUNK + i) * B + b];
    #pragma unroll
    for (int i = 0; i < CHUNK; ++i) buf[1][i] = inp[(size_t)(1 * CHUNK + i) * B + b];

    float s = 0.0f, d = 0.0f;
    float res_s = 0.0f, res_d = 0.0f;

    #pragma unroll
    for (int c = 0; c < NCHUNK; ++c) {
        if (c + 2 < NCHUNK) {
            #pragma unroll
            for (int i = 0; i < CHUNK; ++i)
                buf[(c + 2) % 3][i] = inp[(size_t)((c + 2) * CHUNK + i) * B + b];
        }
        #pragma unroll
        for (int i = 0; i < CHUNK; ++i) {
            const int t = c * CHUNK + i;          // compile-time constant
            const float elapsed = buf[c % 3][i].x;
            const float rating  = buf[c % 3][i].y;

            const float ss     = fmaxf(s, FSRS_S_MIN);
            const float inv_ss = __builtin_amdgcn_rcpf(ss);
            const float lss    = log2f(ss);
            const float r      = exp2f(elapsed * inv_ss * L09);   // 0.9^(elapsed/ss)
            const float omr    = 1.0f - r;

            float nd = fmaf(w4, rating - 3.0f, d);
            nd = fmaf(c_nd, nd, b_nd);
            nd = fminf(fmaxf(nd, 1.0f), 10.0f);
            const float lnd = log2f(nd);

            const bool up = rating > 1.0f;

            // one exp2 for the pow-product, one for the gain, chosen by predicate
            const float eP = up ? fmaf(w7, lnd, fmaf(w8, lss, lw6))
                                : fmaf(w11, lnd, w12 * lss);
            const float eG = omr * (up ? g9 : g13);
            const float pw = exp2f(eP);
            const float g  = exp2f(eG) - 1.0f;

            float ns = up ? ss * fmaf(pw, g, 1.0f) : (w10 * pw) * g;

            if (t == 0) {   // folds at compile time: first-step override
                ns = fmaf(a0, rating, b0);
                nd = fminf(fmaxf(fmaf(a1, rating, b1), 1.0f), 10.0f);
            }

            s = fminf(fmaxf(ns, FSRS_S_MIN), FSRS_S_MAX);
            d = nd;

            if (t == Lm1) { res_s = s; res_d = d; }   // 2 cndmask
        }
    }

    const float ret = exp2f(dt * __builtin_amdgcn_rcpf(res_s) * L09);

    out[b]         = ret;
    out[B + b]     = res_s;
    out[2 * B + b] = res_d;
}

extern "C" void kernel_launch(void* const* d_in, const int* in_sizes, int n_in,
                              void* d_out, int out_size, void* d_ws, size_t ws_size,
                              hipStream_t stream) {
    const float* inputs   = (const float*)d_in[0];   // [64, B, 2] f32
    const float* delta_ts = (const float*)d_in[1];   // [B] f32
    const float* w        = (const float*)d_in[2];   // [14] f32
    const int*   seq_lens = (const int*)d_in[3];     // [B] i32
    float* out = (float*)d_out;                      // [3, B] f32

    const int B = in_sizes[1];
    const int block = 256;
    const int grid  = (B + block - 1) / block;
    fsrs2_kernel<<<grid, block, 0, stream>>>(inputs, delta_ts, w, seq_lens, out, B);
}